// Round 3
// baseline (271.642 us; speedup 1.0000x reference)
//
#include <hip/hip_runtime.h>

// VectorQuantizer: fp32 buffers holding bf16-valued data. in [32,64,64,64]
// NCHW, emb [512,64], out fp32 NCHW. The harness's np reference computes
// distances IN FP32; near-ties force bit-exact replication of:
//   a2 = np.sum(x*x,1)        -> numpy pairwise-8 summation
//   b2 = np.sum(e*e,1)        -> numpy pairwise-8 summation
//   ab = sgemm(x, e.T)        -> sequential k-ascending FMA chain
//   d  = fl(fl(a2+b2) - fl(2*ab)); argmin = first min; out = fl(x+fl(q-x))

#define NEMB 512
#define DIM 64

__global__ __launch_bounds__(256, 2) void vq_exact(
    const float* __restrict__ in, const float* __restrict__ emb,
    float* __restrict__ out, int nvec) {
#pragma clang fp contract(off)
  __shared__ float b2s[NEMB];

  // b2 per row, numpy pairwise-8: r[j] = sum_{i=j,j+8,..,j+56} e_i^2 (seq),
  // then ((r0+r1)+(r2+r3))+((r4+r5)+(r6+r7)). Squares rounded (contract off).
  for (int r = threadIdx.x; r < NEMB; r += 256) {
    const float* e = emb + r * DIM;
    float rr[8];
#pragma unroll
    for (int j = 0; j < 8; ++j) {
      float acc = e[j] * e[j];
#pragma unroll
      for (int i = 8; i < DIM; i += 8) {
        acc = acc + e[i + j] * e[i + j];
      }
      rr[j] = acc;
    }
    b2s[r] = ((rr[0] + rr[1]) + (rr[2] + rr[3])) + ((rr[4] + rr[5]) + (rr[6] + rr[7]));
  }
  __syncthreads();

  const int vec = blockIdx.x * 256 + threadIdx.x;
  if (vec >= nvec) return;
  const int b = vec >> 12;   // / (64*64)
  const int hw = vec & 4095;
  const float* xp = in + ((size_t)b << 18) + hw;

  // Gather x (stride 4096 floats; coalesced 256B/wave per channel).
  float x[DIM];
#pragma unroll
  for (int j = 0; j < DIM; ++j) x[j] = xp[(size_t)j << 12];

  // a2: numpy pairwise-8 over x^2.
  float a2;
  {
    float rr[8];
#pragma unroll
    for (int j = 0; j < 8; ++j) {
      float acc = x[j] * x[j];
#pragma unroll
      for (int i = 8; i < DIM; i += 8) {
        acc = acc + x[i + j] * x[i + j];
      }
      rr[j] = acc;
    }
    a2 = ((rr[0] + rr[1]) + (rr[2] + rr[3])) + ((rr[4] + rr[5]) + (rr[6] + rr[7]));
  }

  // Scan all 512 codewords. ab chain: single accumulator, k ascending,
  // fmaf each step (products exact for bf16-valued data; matches BLAS).
  // 4 codewords in flight for FMA-latency hiding; argmin order preserved.
  float best = 3.0e38f;
  int bi = 0;
  for (int k0 = 0; k0 < NEMB; k0 += 4) {
    const float* e0 = emb + ((k0 + 0) << 6);
    const float* e1 = emb + ((k0 + 1) << 6);
    const float* e2 = emb + ((k0 + 2) << 6);
    const float* e3 = emb + ((k0 + 3) << 6);
    float c0 = 0.f, c1 = 0.f, c2 = 0.f, c3 = 0.f;
#pragma unroll
    for (int j = 0; j < DIM; ++j) {
      const float xj = x[j];
      c0 = fmaf(xj, e0[j], c0);
      c1 = fmaf(xj, e1[j], c1);
      c2 = fmaf(xj, e2[j], c2);
      c3 = fmaf(xj, e3[j], c3);
    }
    float cc[4] = {c0, c1, c2, c3};
#pragma unroll
    for (int q = 0; q < 4; ++q) {
      const float t = a2 + b2s[k0 + q];  // fl(a2 + b2)
      const float u = 2.0f * cc[q];      // fl(2*ab), exact
      const float d = t - u;             // fl(t - u)
      if (d < best) { best = d; bi = k0 + q; }  // strict <: first min wins
    }
  }

  // Output: replicate fl(x + fl(q - x)) and scatter NCHW.
  const float* ew = emb + (bi << 6);
  float* op = out + ((size_t)b << 18) + hw;
#pragma unroll
  for (int c = 0; c < DIM; ++c) {
    const float xv = x[c];
    const float qv = ew[c];
    const float st = xv + (qv - xv);
    op[(size_t)c << 12] = st;
  }
}

extern "C" void kernel_launch(void* const* d_in, const int* in_sizes, int n_in,
                              void* d_out, int out_size, void* d_ws, size_t ws_size,
                              hipStream_t stream) {
  // Disambiguate input order via sizes (embedding = 512*64 = 32768 elements).
  const float* in;
  const float* emb;
  int in_elems;
  if (n_in >= 2 && in_sizes[0] == NEMB * DIM && in_sizes[1] != NEMB * DIM) {
    emb = (const float*)d_in[0];
    in = (const float*)d_in[1];
    in_elems = in_sizes[1];
  } else {
    in = (const float*)d_in[0];
    emb = (const float*)d_in[1];
    in_elems = in_sizes[0];
  }
  const int nvec = in_elems / DIM;              // 131072
  const int blocks = (nvec + 255) / 256;        // 512
  float* out = (float*)d_out;
  vq_exact<<<dim3(blocks), dim3(256), 0, stream>>>(in, emb, out, nvec);
}